// Round 18
// baseline (998.902 us; speedup 1.0000x reference)
//
#include <hip/hip_runtime.h>
#include <hip/hip_bf16.h>
#include <math.h>

#define B_ 32
#define S_ 64
#define T_ 64
#define V_ 32000
#define E_ 512
#define H_ 1024

typedef __attribute__((ext_vector_type(8))) short short8;
typedef __attribute__((ext_vector_type(4))) float f32x4;

static __device__ __forceinline__ unsigned short f2bf(float f) {
  union { float f; unsigned u; } c; c.f = f;
  unsigned r = (c.u + 0x7fffu + ((c.u >> 16) & 1u)) >> 16;  // RNE
  return (unsigned short)r;
}

// ---------- fused embed + f64-accumulate GEMM, BOTH problems in one launch ----------
__global__ __launch_bounds__(256)
void dgemm_embed_dual(const int* __restrict__ idx0, const float* __restrict__ emb0,
                      const float* __restrict__ B0, const float* __restrict__ bias0,
                      float* __restrict__ C0,
                      const int* __restrict__ idx1, const float* __restrict__ emb1,
                      const float* __restrict__ B1, const float* __restrict__ bias1,
                      float* __restrict__ C1, int M, int N, int K) {
  const int half = blockIdx.x >> 9;
  const int bid = blockIdx.x & 511;
  const int* __restrict__ idx = half ? idx1 : idx0;
  const float* __restrict__ emb = half ? emb1 : emb0;
  const float* __restrict__ B = half ? B1 : B0;
  const float* __restrict__ bias = half ? bias1 : bias0;
  float* __restrict__ C = half ? C1 : C0;

  __shared__ float As[32][68];  // [k][m], padded to 16B multiple
  __shared__ float Bs[32][64];  // [k][n]
  const int nbm = M >> 6;
  const int bm = bid % nbm;
  const int bn = bid / nbm;
  const int tid = threadIdx.x;
  const int tr = tid >> 4, tc = tid & 15;

  const int arow = tid >> 3, acol = (tid & 7) * 4;
  const float* arp[2];
#pragma unroll
  for (int p = 0; p < 2; ++p) {
    int r = arow + p * 32;
    arp[p] = emb + (size_t)idx[bm * 64 + r] * E_;
  }

  double acc[4][4] = {};

  for (int kt = 0; kt < K; kt += 32) {
    {
#pragma unroll
      for (int p = 0; p < 2; ++p) {
        int r = arow + p * 32;
        float4 v = *(const float4*)(arp[p] + kt + acol);
        As[acol + 0][r] = v.x; As[acol + 1][r] = v.y;
        As[acol + 2][r] = v.z; As[acol + 3][r] = v.w;
      }
      int brow = tid >> 4, bcol = (tid & 15) * 4;
#pragma unroll
      for (int p = 0; p < 2; ++p) {
        int r = brow + p * 16;
        float4 v = *(const float4*)(B + (size_t)(kt + r) * N + bn * 64 + bcol);
        *(float4*)(&Bs[r][bcol]) = v;
      }
    }
    __syncthreads();
#pragma unroll
    for (int k = 0; k < 32; ++k) {
      float4 av = *(const float4*)(&As[k][tr * 4]);
      float4 bv = *(const float4*)(&Bs[k][tc * 4]);
      double a[4] = {(double)av.x, (double)av.y, (double)av.z, (double)av.w};
      double b[4] = {(double)bv.x, (double)bv.y, (double)bv.z, (double)bv.w};
#pragma unroll
      for (int i = 0; i < 4; ++i)
#pragma unroll
        for (int j = 0; j < 4; ++j) acc[i][j] = fma(a[i], b[j], acc[i][j]);
    }
    __syncthreads();
  }
#pragma unroll
  for (int i = 0; i < 4; ++i) {
    int gm = bm * 64 + tr * 4 + i;
    int gn = bn * 64 + tc * 4;
    float4 o;
    o.x = (float)(acc[i][0] + (double)bias[gn + 0]);
    o.y = (float)(acc[i][1] + (double)bias[gn + 1]);
    o.z = (float)(acc[i][2] + (double)bias[gn + 2]);
    o.w = (float)(acc[i][3] + (double)bias[gn + 3]);
    *(float4*)(C + (size_t)gm * N + gn) = o;
  }
}

// ---------- transpose fp32 [K][N] -> fp32 [N][K], both Whh in one launch ----------
__global__ __launch_bounds__(256)
void transpose_f32_dual(const float* __restrict__ W0, float* __restrict__ WT0,
                        const float* __restrict__ W1, float* __restrict__ WT1,
                        int K, int N) {
  const int half = blockIdx.y >> 4;
  const int by = blockIdx.y & 15;
  const float* __restrict__ W = half ? W1 : W0;
  float* __restrict__ WT = half ? WT1 : WT0;
  __shared__ float t[64][65];
  int k0 = blockIdx.x * 64;
  int n0 = by * 64;
  int tid = threadIdx.x;
  int r = tid >> 4, c4 = tid & 15;
#pragma unroll
  for (int i = 0; i < 4; ++i) {
    int row = r + i * 16;
    float4 v = *(const float4*)(W + (size_t)(k0 + row) * N + n0 + c4 * 4);
    t[row][c4 * 4 + 0] = v.x; t[row][c4 * 4 + 1] = v.y;
    t[row][c4 * 4 + 2] = v.z; t[row][c4 * 4 + 3] = v.w;
  }
  __syncthreads();
#pragma unroll
  for (int i = 0; i < 4; ++i) {
    int n = r + i * 16;
    float4 o;
    o.x = t[c4 * 4 + 0][n]; o.y = t[c4 * 4 + 1][n];
    o.z = t[c4 * 4 + 2][n]; o.w = t[c4 * 4 + 3][n];
    *(float4*)(WT + (size_t)(n0 + n) * K + k0 + c4 * 4) = o;
  }
}

// ---------- transpose fp32 [K][N] -> bf16 [N][K] ----------
__global__ __launch_bounds__(256)
void transpose_bf16(const float* __restrict__ W, unsigned short* __restrict__ WT,
                    int K, int N) {
  __shared__ float t[64][65];
  int k0 = blockIdx.x * 64;
  int n0 = blockIdx.y * 64;
  int tid = threadIdx.x;
  int r = tid >> 4, c4 = tid & 15;
#pragma unroll
  for (int i = 0; i < 4; ++i) {
    int row = r + i * 16;
    float4 v = *(const float4*)(W + (size_t)(k0 + row) * N + n0 + c4 * 4);
    t[row][c4 * 4 + 0] = v.x; t[row][c4 * 4 + 1] = v.y;
    t[row][c4 * 4 + 2] = v.z; t[row][c4 * 4 + 3] = v.w;
  }
  __syncthreads();
#pragma unroll
  for (int i = 0; i < 4; ++i) {
    int n = r + i * 16;
    ushort4 o;
    o.x = f2bf(t[c4 * 4 + 0][n]); o.y = f2bf(t[c4 * 4 + 1][n]);
    o.z = f2bf(t[c4 * 4 + 2][n]); o.w = f2bf(t[c4 * 4 + 3][n]);
    *(ushort4*)(WT + (size_t)(n0 + n) * K + k0 + c4 * 4) = o;
  }
}

// ---------- bf16 MFMA GEMM: C[M,N] = A[M,K] * BT[N,K]^T + bias ----------
// 128x128 tile, XOR-swizzled LDS, XCD swizzle, T14 reg-prefetch, LDS-staged
// coalesced epilogue (r17 proven form, FROZEN).
__global__ __launch_bounds__(256)
void gemm_bt_swap(const unsigned short* __restrict__ A, const unsigned short* __restrict__ BT,
                  const float* __restrict__ bias, float* __restrict__ C,
                  int M, int N, int K) {
  __shared__ unsigned short AsBs[2][128 * 64];
  unsigned short* As = AsBs[0];
  unsigned short* Bs = AsBs[1];
  const int nbm = M >> 7;
  int idx = blockIdx.x;
  const int cpx = gridDim.x >> 3;
  idx = (idx & 7) * cpx + (idx >> 3);
  const int bm = idx % nbm;
  const int bn = idx / nbm;
  const int tid = threadIdx.x;
  const int lane = tid & 63;
  const int wr = (tid >> 6) >> 1;
  const int wc = (tid >> 6) & 1;

  f32x4 acc[4][4] = {};

  int srow[4], scol8[4], ssw[4];
#pragma unroll
  for (int i = 0; i < 4; ++i) {
    int c = i * 256 + tid;
    srow[i] = c >> 3; scol8[i] = c & 7;
    ssw[i] = scol8[i] ^ (srow[i] & 7);
  }

  short8 av[4], bv[4];
#pragma unroll
  for (int i = 0; i < 4; ++i) {
    av[i] = *(const short8*)(A + (size_t)(bm * 128 + srow[i]) * K + scol8[i] * 8);
    bv[i] = *(const short8*)(BT + (size_t)(bn * 128 + srow[i]) * K + scol8[i] * 8);
  }

  for (int kt = 0; kt < K; kt += 64) {
#pragma unroll
    for (int i = 0; i < 4; ++i) {
      *(short8*)(As + srow[i] * 64 + ssw[i] * 8) = av[i];
      *(short8*)(Bs + srow[i] * 64 + ssw[i] * 8) = bv[i];
    }
    __syncthreads();

    if (kt + 64 < K) {
#pragma unroll
      for (int i = 0; i < 4; ++i) {
        av[i] = *(const short8*)(A + (size_t)(bm * 128 + srow[i]) * K + kt + 64 + scol8[i] * 8);
        bv[i] = *(const short8*)(BT + (size_t)(bn * 128 + srow[i]) * K + kt + 64 + scol8[i] * 8);
      }
    }

#pragma unroll
    for (int kk = 0; kk < 64; kk += 32) {
      int kc = (kk + ((lane >> 4) << 3)) >> 3;
      short8 af[4], bfr[4];
#pragma unroll
      for (int mi = 0; mi < 4; ++mi) {
        int row = wr * 64 + mi * 16 + (lane & 15);
        af[mi] = *(const short8*)(As + row * 64 + ((kc ^ (row & 7)) << 3));
      }
#pragma unroll
      for (int ni = 0; ni < 4; ++ni) {
        int row = wc * 64 + ni * 16 + (lane & 15);
        bfr[ni] = *(const short8*)(Bs + row * 64 + ((kc ^ (row & 7)) << 3));
      }
#pragma unroll
      for (int mi = 0; mi < 4; ++mi)
#pragma unroll
        for (int ni = 0; ni < 4; ++ni)
          acc[mi][ni] = __builtin_amdgcn_mfma_f32_16x16x32_bf16(
              af[mi], bfr[ni], acc[mi][ni], 0, 0, 0);
    }
    __syncthreads();
  }

  float* Ct = (float*)AsBs;  // 32 x 132 f32 (staging LDS is dead)
  const int cq = (lane >> 4) << 2;
  const int cn = lane & 15;
#pragma unroll
  for (int mi = 0; mi < 4; ++mi) {
    if (mi) __syncthreads();
#pragma unroll
    for (int ni = 0; ni < 4; ++ni) {
      int gn = bn * 128 + wc * 64 + ni * 16 + cn;
      float bvv = bias[gn];
#pragma unroll
      for (int q = 0; q < 4; ++q)
        Ct[(wr * 16 + cq + q) * 132 + wc * 64 + ni * 16 + cn] =
            acc[mi][ni][q] + bvv;
    }
    __syncthreads();
#pragma unroll
    for (int p = 0; p < 4; ++p) {
      int f = p * 256 + tid;
      int r = f >> 5, c4 = f & 31;
      float4 v = *(const float4*)(Ct + r * 132 + c4 * 4);
      int gm = bm * 128 + (r >> 4) * 64 + mi * 16 + (r & 15);
      int b = gm & (B_ - 1);
      int t = gm >> 5;
      float* dstp = &C[((size_t)b * T_ + t) * N + bn * 128 + c4 * 4];
      __builtin_nontemporal_store(v.x, dstp + 0);
      __builtin_nontemporal_store(v.y, dstp + 1);
      __builtin_nontemporal_store(v.z, dstp + 2);
      __builtin_nontemporal_store(v.w, dstp + 3);
    }
  }
}

// ---------- persistent group-local RNN scan (r12 compute, FLAG barrier) ----------
// 8 independent 4-batch chains (group = blockIdx&7), 32 blocks/chain.
// Barrier v2: per-block FLAG STORES instead of a shared RMW counter. 32
// atomic fetch_adds to one line serialize at the coherence point (~1.3-2.5
// us/step — r14's 64-arrival doubling is the evidence); 32 plain stores
// combine, and wave 0 polls the whole 128B flag line with ONE coalesced
// load (lane&31 -> 2 lanes/flag, __all(v>=t+1)). Ordering unchanged:
// per-wave vmcnt(0) + syncthreads before the flag store. Monotonic flags,
// memset-0 init -> deadlock-free. All arithmetic verbatim r12/r17.
__global__ __launch_bounds__(512)
void rnn_scan_grp2(const float* __restrict__ xe, const float* __restrict__ xd,
                   const float* __restrict__ WTe, const float* __restrict__ WTd,
                   const float* __restrict__ bhhE, const float* __restrict__ bhhD,
                   float* __restrict__ hA, float* __restrict__ hB,
                   unsigned short* __restrict__ hsb, unsigned* __restrict__ bar) {
  __shared__ float hl[4 * 1024];  // 16 KB chain h-slice
  const int tid = threadIdx.x;
  const int grp = blockIdx.x & 7;
  const int jslot = blockIdx.x >> 3;
  const int jbase = jslot * 32;
  const int bg = grp * 4;
  const int w = tid >> 6;  // wave -> j-quad
  const int l = tid & 63;  // k-split lane
  unsigned* flg = bar + grp * 64;  // 32 flags in one 128B line; groups 256B apart

  const int a = 8 * (l & 1) + 4 * ((l >> 1) & 1) + 2 * ((l >> 2) & 1) +
                ((l >> 3) & 1);
  const int lb = a >> 2;
  const int gb = bg + lb;
  const int gj = jbase + w * 4 + (a & 3);
  const float bje = bhhE[gj];
  const float bjd = bhhD[gj];

  float4 wreg[4][4];
  {
    const float* wsrc = WTe + (size_t)(jbase + w * 4) * 1024;
#pragma unroll
    for (int i = 0; i < 4; ++i) {
      int g = l + 64 * i;
#pragma unroll
      for (int ji = 0; ji < 4; ++ji)
        wreg[i][ji] = *(const float4*)(wsrc + (size_t)ji * 1024 + g * 4);
    }
  }

  for (int t = 0; t < 128; ++t) {
    if (t == 64) {
      const float* wsrc = WTd + (size_t)(jbase + w * 4) * 1024;
#pragma unroll
      for (int i = 0; i < 4; ++i) {
        int g = l + 64 * i;
#pragma unroll
        for (int ji = 0; ji < 4; ++ji)
          wreg[i][ji] = *(const float4*)(wsrc + (size_t)ji * 1024 + g * 4);
      }
    }
    const bool enc = (t < 64);
    const int s = t & 63;
    const float* __restrict__ h_in = (t & 1) ? hB : hA;
    float* __restrict__ h_out = (t & 1) ? hA : hB;
    const float* __restrict__ x = enc ? xe : xd;

    float xv = x[((size_t)gb * 64 + s) * H_ + gj];

    {
      const float* hsrc = h_in + bg * H_;
      float v[8];
#pragma unroll
      for (int u = 0; u < 8; ++u)
        v[u] = __hip_atomic_load(hsrc + u * 512 + tid, __ATOMIC_RELAXED,
                                 __HIP_MEMORY_SCOPE_AGENT);
#pragma unroll
      for (int u = 0; u < 8; ++u)
        hl[u * 512 + tid] = v[u];
    }
    __syncthreads();

    double acc[4][4];
#pragma unroll
    for (int bi = 0; bi < 4; ++bi)
#pragma unroll
      for (int ji = 0; ji < 4; ++ji) acc[bi][ji] = 0.;

#pragma unroll
    for (int i = 0; i < 4; ++i) {
      int g = l + 64 * i;
      float4 hv[4];
#pragma unroll
      for (int bi = 0; bi < 4; ++bi)
        hv[bi] = *(const float4*)(hl + bi * 1024 + g * 4);
#pragma unroll
      for (int bi = 0; bi < 4; ++bi)
#pragma unroll
        for (int ji = 0; ji < 4; ++ji) {
          acc[bi][ji] = fma((double)hv[bi].x, (double)wreg[i][ji].x, acc[bi][ji]);
          acc[bi][ji] = fma((double)hv[bi].y, (double)wreg[i][ji].y, acc[bi][ji]);
          acc[bi][ji] = fma((double)hv[bi].z, (double)wreg[i][ji].z, acc[bi][ji]);
          acc[bi][ji] = fma((double)hv[bi].w, (double)wreg[i][ji].w, acc[bi][ji]);
        }
    }

    double r8[8], r4[4], r2[2], r1;
#pragma unroll
    for (int aa = 0; aa < 8; ++aa) {
      double send = (l & 1) ? acc[aa >> 2][aa & 3] : acc[(aa + 8) >> 2][(aa + 8) & 3];
      double mine = (l & 1) ? acc[(aa + 8) >> 2][(aa + 8) & 3] : acc[aa >> 2][aa & 3];
      r8[aa] = mine + __shfl_xor(send, 1);
    }
#pragma unroll
    for (int aa = 0; aa < 4; ++aa) {
      double send = (l & 2) ? r8[aa] : r8[aa + 4];
      double mine = (l & 2) ? r8[aa + 4] : r8[aa];
      r4[aa] = mine + __shfl_xor(send, 2);
    }
#pragma unroll
    for (int aa = 0; aa < 2; ++aa) {
      double send = (l & 4) ? r4[aa] : r4[aa + 2];
      double mine = (l & 4) ? r4[aa + 2] : r4[aa];
      r2[aa] = mine + __shfl_xor(send, 4);
    }
    {
      double send = (l & 8) ? r2[0] : r2[1];
      double mine = (l & 8) ? r2[1] : r2[0];
      r1 = mine + __shfl_xor(send, 8);
    }
    r1 += __shfl_xor(r1, 16);
    r1 += __shfl_xor(r1, 32);

    float hf = 0.f;
    if (l < 16) {
      double v = r1 + (double)xv + (double)(enc ? bje : bjd);
      double h = tanh(v);
      hf = (float)h;
      __hip_atomic_store(&h_out[(size_t)gb * H_ + gj], hf, __ATOMIC_RELAXED,
                         __HIP_MEMORY_SCOPE_AGENT);
    }

    // ---- flag barrier: store own slot, wave 0 polls the whole line ----
    if (t < 127) {
      asm volatile("s_waitcnt vmcnt(0)" ::: "memory");  // h stores ack'd
      __syncthreads();                                   // all waves drained
      if (tid == 0)
        __hip_atomic_store(&flg[jslot], (unsigned)(t + 1), __ATOMIC_RELAXED,
                           __HIP_MEMORY_SCOPE_AGENT);
      if (tid < 64) {
        const unsigned tgt = (unsigned)(t + 1);
        for (;;) {
          unsigned v = __hip_atomic_load(&flg[l & 31], __ATOMIC_RELAXED,
                                         __HIP_MEMORY_SCOPE_AGENT);
          if (__all(v >= tgt)) break;
          __builtin_amdgcn_s_sleep(1);
        }
      }
      __syncthreads();
    }
    // hsb NT-store AFTER the barrier: its ack overlaps next step's staging
    if (!enc && l < 16)
      __builtin_nontemporal_store(f2bf(hf),
                                  &hsb[(size_t)s * (B_ * H_) + (size_t)gb * H_ + gj]);
  }
}

// ---------- log-softmax, row staged in LDS (one HBM read + one write) ----------
__global__ __launch_bounds__(1024)
void log_softmax_rows(float* __restrict__ out) {
  __shared__ float rl[32000];  // 125 KB row stage
  __shared__ float wm[16], wsv[16];
  float* row = out + (size_t)blockIdx.x * V_;
  const int tid = threadIdx.x;
  float m = -INFINITY, s = 0.f;
  for (int i = tid; i < V_ / 4; i += 1024) {
    float4 v = *(const float4*)(row + i * 4);
    *(float4*)(rl + i * 4) = v;
    float mx = fmaxf(fmaxf(v.x, v.y), fmaxf(v.z, v.w));
    if (mx > m) { s *= __expf(m - mx); m = mx; }
    s += __expf(v.x - m) + __expf(v.y - m) + __expf(v.z - m) + __expf(v.w - m);
  }
#pragma unroll
  for (int o = 32; o; o >>= 1) {
    float mo = __shfl_xor(m, o);
    float so = __shfl_xor(s, o);
    float mn = fmaxf(m, mo);
    s = s * __expf(m - mn) + so * __expf(mo - mn);
    m = mn;
  }
  int wv = tid >> 6;
  if ((tid & 63) == 0) { wm[wv] = m; wsv[wv] = s; }
  __syncthreads();
  float M = wm[0];
#pragma unroll
  for (int i = 1; i < 16; ++i) M = fmaxf(M, wm[i]);
  float Ssum = 0.f;
#pragma unroll
  for (int i = 0; i < 16; ++i) Ssum += wsv[i] * __expf(wm[i] - M);
  float L = M + logf(Ssum);
  for (int i = tid; i < V_ / 4; i += 1024) {
    float4 v = *(const float4*)(rl + i * 4);
    v.x -= L; v.y -= L; v.z -= L; v.w -= L;
    __builtin_nontemporal_store(v.x, &row[i * 4 + 0]);
    __builtin_nontemporal_store(v.y, &row[i * 4 + 1]);
    __builtin_nontemporal_store(v.z, &row[i * 4 + 2]);
    __builtin_nontemporal_store(v.w, &row[i * 4 + 3]);
  }
}

extern "C" void kernel_launch(void* const* d_in, const int* in_sizes, int n_in,
                              void* d_out, int out_size, void* d_ws, size_t ws_size,
                              hipStream_t stream) {
  const int*   src  = (const int*)  d_in[0];
  const int*   tgt  = (const int*)  d_in[1];
  const float* encE = (const float*)d_in[2];
  const float* decE = (const float*)d_in[3];
  const float* WihE = (const float*)d_in[4];
  const float* bihE = (const float*)d_in[5];
  const float* WhhE = (const float*)d_in[6];
  const float* bhhE = (const float*)d_in[7];
  const float* WihD = (const float*)d_in[8];
  const float* bihD = (const float*)d_in[9];
  const float* WhhD = (const float*)d_in[10];
  const float* bhhD = (const float*)d_in[11];
  const float* Wout = (const float*)d_in[12];
  const float* bout = (const float*)d_in[13];
  float* out = (float*)d_out;

  char* w = (char*)d_ws;
  float* x_e = (float*)w;                      w += (size_t)2048 * 1024 * 4;
  float* x_d = (float*)w;                      w += (size_t)2048 * 1024 * 4;
  float* h0  = (float*)w;                      w += 32 * 1024 * 4;
  float* h1  = (float*)w;                      w += 32 * 1024 * 4;
  unsigned* bar = (unsigned*)w;                w += 8 * 64 * 4;  // 8 flag lines, 256B apart
  float* WhhTe = (float*)w;                    w += (size_t)1024 * 1024 * 4;
  float* WhhTd = (float*)w;                    w += (size_t)1024 * 1024 * 4;
  unsigned short* hsb   = (unsigned short*)w;  w += (size_t)2048 * 1024 * 2;
  unsigned short* WoutT = (unsigned short*)w;  w += (size_t)V_ * 1024 * 2;

  // Input projections, both problems fused into one launch
  dgemm_embed_dual<<<1024, 256, 0, stream>>>(src, encE, WihE, bihE, x_e,
                                             tgt, decE, WihD, bihD, x_d,
                                             2048, H_, E_);

  // Pre-transpose both recurrence weight matrices in one launch
  transpose_f32_dual<<<dim3(H_ / 64, 2 * (H_ / 64)), 256, 0, stream>>>(
      WhhE, WhhTe, WhhD, WhhTd, H_, H_);

  // Persistent group-local scan (8 independent 4-batch chains, flag barrier)
  hipMemsetAsync(h0, 0, 32 * 1024 * 4, stream);
  hipMemsetAsync(bar, 0, 8 * 64 * 4, stream);
  rnn_scan_grp2<<<256, 512, 0, stream>>>(x_e, x_d, WhhTe, WhhTd, bhhE, bhhD,
                                         h0, h1, hsb, bar);

  // Logits: out[b][t][:] = hs[t*B+b] @ Wout + bout  (bf16 MFMA, raw logits)
  transpose_bf16<<<dim3(H_ / 64, V_ / 64), 256, 0, stream>>>(Wout, WoutT, H_, V_);
  gemm_bt_swap<<<(2048 / 128) * (V_ / 128), 256, 0, stream>>>(hsb, WoutT, bout, out,
                                                              2048, V_, H_);
  // In-place log-softmax
  log_softmax_rows<<<B_ * T_, 1024, 0, stream>>>(out);
}

// Round 19
// 957.351 us; speedup vs baseline: 1.0434x; 1.0434x over previous
//
#include <hip/hip_runtime.h>
#include <hip/hip_bf16.h>
#include <math.h>

#define B_ 32
#define S_ 64
#define T_ 64
#define V_ 32000
#define E_ 512
#define H_ 1024

typedef __attribute__((ext_vector_type(8))) short short8;
typedef __attribute__((ext_vector_type(4))) float f32x4;

static __device__ __forceinline__ unsigned short f2bf(float f) {
  union { float f; unsigned u; } c; c.f = f;
  unsigned r = (c.u + 0x7fffu + ((c.u >> 16) & 1u)) >> 16;  // RNE
  return (unsigned short)r;
}

// ---------- fused prologue: dual embed-dgemm + Whh transposes + Wout->bf16 ----------
// All three roles are mutually independent; block ranges select the role.
//   [0, 1024)      : dual f64-accum embed GEMM (x_e / x_d)        [compute]
//   [1024, 1536)   : transpose_f32 of WhhE/WhhD -> WhhT           [HBM]
//   [1536, 9536)   : transpose fp32->bf16 of Wout -> WoutT        [HBM]
// HBM-bound transpose blocks fill CU capacity under the compute-bound dgemm.
// Per-role bodies are verbatim r17/r18 -> bit-identical outputs.
__global__ __launch_bounds__(256)
void prologue(const int* __restrict__ src, const float* __restrict__ encE,
              const float* __restrict__ WihE, const float* __restrict__ bihE,
              float* __restrict__ x_e,
              const int* __restrict__ tgt, const float* __restrict__ decE,
              const float* __restrict__ WihD, const float* __restrict__ bihD,
              float* __restrict__ x_d,
              const float* __restrict__ WhhE, float* __restrict__ WhhTe,
              const float* __restrict__ WhhD, float* __restrict__ WhhTd,
              const float* __restrict__ Wout, unsigned short* __restrict__ WoutT) {
  __shared__ float smem[4224];
  const int bid = blockIdx.x;
  const int tid = threadIdx.x;

  if (bid < 1024) {
    // ---- dual embed dgemm ----
    const int half = bid >> 9;
    const int b9 = bid & 511;
    const int* __restrict__ idx = half ? tgt : src;
    const float* __restrict__ emb = half ? decE : encE;
    const float* __restrict__ Bm = half ? WihD : WihE;
    const float* __restrict__ bias = half ? bihD : bihE;
    float* __restrict__ C = half ? x_d : x_e;
    float (*As)[68] = (float(*)[68])smem;
    float (*Bs)[64] = (float(*)[64])(smem + 32 * 68);
    const int bm = b9 & 31;        // M=2048 -> nbm=32
    const int bn = b9 >> 5;
    const int tr = tid >> 4, tc = tid & 15;

    const int arow = tid >> 3, acol = (tid & 7) * 4;
    const float* arp[2];
#pragma unroll
    for (int p = 0; p < 2; ++p)
      arp[p] = emb + (size_t)idx[bm * 64 + arow + p * 32] * E_;

    double acc[4][4] = {};
    for (int kt = 0; kt < E_; kt += 32) {
#pragma unroll
      for (int p = 0; p < 2; ++p) {
        int r = arow + p * 32;
        float4 v = *(const float4*)(arp[p] + kt + acol);
        As[acol + 0][r] = v.x; As[acol + 1][r] = v.y;
        As[acol + 2][r] = v.z; As[acol + 3][r] = v.w;
      }
      int brow = tid >> 4, bcol = (tid & 15) * 4;
#pragma unroll
      for (int p = 0; p < 2; ++p) {
        int r = brow + p * 16;
        float4 v = *(const float4*)(Bm + (size_t)(kt + r) * H_ + bn * 64 + bcol);
        *(float4*)(&Bs[r][bcol]) = v;
      }
      __syncthreads();
#pragma unroll
      for (int k = 0; k < 32; ++k) {
        float4 av = *(const float4*)(&As[k][tr * 4]);
        float4 bv = *(const float4*)(&Bs[k][tc * 4]);
        double a[4] = {(double)av.x, (double)av.y, (double)av.z, (double)av.w};
        double b[4] = {(double)bv.x, (double)bv.y, (double)bv.z, (double)bv.w};
#pragma unroll
        for (int i = 0; i < 4; ++i)
#pragma unroll
          for (int j = 0; j < 4; ++j) acc[i][j] = fma(a[i], b[j], acc[i][j]);
      }
      __syncthreads();
    }
#pragma unroll
    for (int i = 0; i < 4; ++i) {
      int gm = bm * 64 + tr * 4 + i;
      int gn = bn * 64 + tc * 4;
      float4 o;
      o.x = (float)(acc[i][0] + (double)bias[gn + 0]);
      o.y = (float)(acc[i][1] + (double)bias[gn + 1]);
      o.z = (float)(acc[i][2] + (double)bias[gn + 2]);
      o.w = (float)(acc[i][3] + (double)bias[gn + 3]);
      *(float4*)(C + (size_t)gm * H_ + gn) = o;
    }
  } else if (bid < 1536) {
    // ---- Whh transposes (f32) ----
    int t6 = bid - 1024;
    int k0 = (t6 & 15) * 64;
    int byf = t6 >> 4;            // 0..31
    const float* __restrict__ W = (byf >> 4) ? WhhD : WhhE;
    float* __restrict__ WT = (byf >> 4) ? WhhTd : WhhTe;
    int n0 = (byf & 15) * 64;
    float (*tld)[65] = (float(*)[65])smem;
    int r = tid >> 4, c4 = tid & 15;
#pragma unroll
    for (int i = 0; i < 4; ++i) {
      int row = r + i * 16;
      float4 v = *(const float4*)(W + (size_t)(k0 + row) * H_ + n0 + c4 * 4);
      tld[row][c4 * 4 + 0] = v.x; tld[row][c4 * 4 + 1] = v.y;
      tld[row][c4 * 4 + 2] = v.z; tld[row][c4 * 4 + 3] = v.w;
    }
    __syncthreads();
#pragma unroll
    for (int i = 0; i < 4; ++i) {
      int n = r + i * 16;
      float4 o;
      o.x = tld[c4 * 4 + 0][n]; o.y = tld[c4 * 4 + 1][n];
      o.z = tld[c4 * 4 + 2][n]; o.w = tld[c4 * 4 + 3][n];
      *(float4*)(WT + (size_t)(n0 + n) * H_ + k0 + c4 * 4) = o;
    }
  } else {
    // ---- Wout transpose fp32 -> bf16 ----
    int t6 = bid - 1536;          // 0..7999 = dim(16, 500)
    int k0 = (t6 & 15) * 64;      // K = H_ = 1024
    int n0 = (t6 >> 4) * 64;      // N = V_ = 32000
    float (*tld)[65] = (float(*)[65])smem;
    int r = tid >> 4, c4 = tid & 15;
#pragma unroll
    for (int i = 0; i < 4; ++i) {
      int row = r + i * 16;
      float4 v = *(const float4*)(Wout + (size_t)(k0 + row) * V_ + n0 + c4 * 4);
      tld[row][c4 * 4 + 0] = v.x; tld[row][c4 * 4 + 1] = v.y;
      tld[row][c4 * 4 + 2] = v.z; tld[row][c4 * 4 + 3] = v.w;
    }
    __syncthreads();
#pragma unroll
    for (int i = 0; i < 4; ++i) {
      int n = r + i * 16;
      ushort4 o;
      o.x = f2bf(tld[c4 * 4 + 0][n]); o.y = f2bf(tld[c4 * 4 + 1][n]);
      o.z = f2bf(tld[c4 * 4 + 2][n]); o.w = f2bf(tld[c4 * 4 + 3][n]);
      *(ushort4*)(WoutT + (size_t)(n0 + n) * H_ + k0 + c4 * 4) = o;
    }
  }
}

// ---------- bf16 MFMA GEMM: C[M,N] = A[M,K] * BT[N,K]^T + bias ----------
// 128x128 tile, XOR-swizzled LDS, XCD swizzle, T14 reg-prefetch, LDS-staged
// coalesced epilogue (r17 proven form, FROZEN).
__global__ __launch_bounds__(256)
void gemm_bt_swap(const unsigned short* __restrict__ A, const unsigned short* __restrict__ BT,
                  const float* __restrict__ bias, float* __restrict__ C,
                  int M, int N, int K) {
  __shared__ unsigned short AsBs[2][128 * 64];
  unsigned short* As = AsBs[0];
  unsigned short* Bs = AsBs[1];
  const int nbm = M >> 7;
  int idx = blockIdx.x;
  const int cpx = gridDim.x >> 3;
  idx = (idx & 7) * cpx + (idx >> 3);
  const int bm = idx % nbm;
  const int bn = idx / nbm;
  const int tid = threadIdx.x;
  const int lane = tid & 63;
  const int wr = (tid >> 6) >> 1;
  const int wc = (tid >> 6) & 1;

  f32x4 acc[4][4] = {};

  int srow[4], scol8[4], ssw[4];
#pragma unroll
  for (int i = 0; i < 4; ++i) {
    int c = i * 256 + tid;
    srow[i] = c >> 3; scol8[i] = c & 7;
    ssw[i] = scol8[i] ^ (srow[i] & 7);
  }

  short8 av[4], bv[4];
#pragma unroll
  for (int i = 0; i < 4; ++i) {
    av[i] = *(const short8*)(A + (size_t)(bm * 128 + srow[i]) * K + scol8[i] * 8);
    bv[i] = *(const short8*)(BT + (size_t)(bn * 128 + srow[i]) * K + scol8[i] * 8);
  }

  for (int kt = 0; kt < K; kt += 64) {
#pragma unroll
    for (int i = 0; i < 4; ++i) {
      *(short8*)(As + srow[i] * 64 + ssw[i] * 8) = av[i];
      *(short8*)(Bs + srow[i] * 64 + ssw[i] * 8) = bv[i];
    }
    __syncthreads();

    if (kt + 64 < K) {
#pragma unroll
      for (int i = 0; i < 4; ++i) {
        av[i] = *(const short8*)(A + (size_t)(bm * 128 + srow[i]) * K + kt + 64 + scol8[i] * 8);
        bv[i] = *(const short8*)(BT + (size_t)(bn * 128 + srow[i]) * K + kt + 64 + scol8[i] * 8);
      }
    }

#pragma unroll
    for (int kk = 0; kk < 64; kk += 32) {
      int kc = (kk + ((lane >> 4) << 3)) >> 3;
      short8 af[4], bfr[4];
#pragma unroll
      for (int mi = 0; mi < 4; ++mi) {
        int row = wr * 64 + mi * 16 + (lane & 15);
        af[mi] = *(const short8*)(As + row * 64 + ((kc ^ (row & 7)) << 3));
      }
#pragma unroll
      for (int ni = 0; ni < 4; ++ni) {
        int row = wc * 64 + ni * 16 + (lane & 15);
        bfr[ni] = *(const short8*)(Bs + row * 64 + ((kc ^ (row & 7)) << 3));
      }
#pragma unroll
      for (int mi = 0; mi < 4; ++mi)
#pragma unroll
        for (int ni = 0; ni < 4; ++ni)
          acc[mi][ni] = __builtin_amdgcn_mfma_f32_16x16x32_bf16(
              af[mi], bfr[ni], acc[mi][ni], 0, 0, 0);
    }
    __syncthreads();
  }

  float* Ct = (float*)AsBs;  // 32 x 132 f32 (staging LDS is dead)
  const int cq = (lane >> 4) << 2;
  const int cn = lane & 15;
#pragma unroll
  for (int mi = 0; mi < 4; ++mi) {
    if (mi) __syncthreads();
#pragma unroll
    for (int ni = 0; ni < 4; ++ni) {
      int gn = bn * 128 + wc * 64 + ni * 16 + cn;
      float bvv = bias[gn];
#pragma unroll
      for (int q = 0; q < 4; ++q)
        Ct[(wr * 16 + cq + q) * 132 + wc * 64 + ni * 16 + cn] =
            acc[mi][ni][q] + bvv;
    }
    __syncthreads();
#pragma unroll
    for (int p = 0; p < 4; ++p) {
      int f = p * 256 + tid;
      int r = f >> 5, c4 = f & 31;
      float4 v = *(const float4*)(Ct + r * 132 + c4 * 4);
      int gm = bm * 128 + (r >> 4) * 64 + mi * 16 + (r & 15);
      int b = gm & (B_ - 1);
      int t = gm >> 5;
      float* dstp = &C[((size_t)b * T_ + t) * N + bn * 128 + c4 * 4];
      __builtin_nontemporal_store(v.x, dstp + 0);
      __builtin_nontemporal_store(v.y, dstp + 1);
      __builtin_nontemporal_store(v.z, dstp + 2);
      __builtin_nontemporal_store(v.w, dstp + 3);
    }
  }
}

// ---------- persistent group-local RNN scan (r12/r17 proven form, FROZEN) ----------
// Counter barrier restored (r18's flag barrier was +3%: sync floor = fabric
// RTT, not RMW serialization).
__global__ __launch_bounds__(512)
void rnn_scan_grp2(const float* __restrict__ xe, const float* __restrict__ xd,
                   const float* __restrict__ WTe, const float* __restrict__ WTd,
                   const float* __restrict__ bhhE, const float* __restrict__ bhhD,
                   float* __restrict__ hA, float* __restrict__ hB,
                   unsigned short* __restrict__ hsb, unsigned* __restrict__ bar) {
  __shared__ float hl[4 * 1024];  // 16 KB chain h-slice
  const int tid = threadIdx.x;
  const int grp = blockIdx.x & 7;
  const int jslot = blockIdx.x >> 3;
  const int jbase = jslot * 32;
  const int bg = grp * 4;
  const int w = tid >> 6;  // wave -> j-quad
  const int l = tid & 63;  // k-split lane
  unsigned* mybar = bar + grp * 32;  // 128B-spaced counters

  const int a = 8 * (l & 1) + 4 * ((l >> 1) & 1) + 2 * ((l >> 2) & 1) +
                ((l >> 3) & 1);
  const int lb = a >> 2;
  const int gb = bg + lb;
  const int gj = jbase + w * 4 + (a & 3);
  const float bje = bhhE[gj];
  const float bjd = bhhD[gj];

  float4 wreg[4][4];
  {
    const float* wsrc = WTe + (size_t)(jbase + w * 4) * 1024;
#pragma unroll
    for (int i = 0; i < 4; ++i) {
      int g = l + 64 * i;
#pragma unroll
      for (int ji = 0; ji < 4; ++ji)
        wreg[i][ji] = *(const float4*)(wsrc + (size_t)ji * 1024 + g * 4);
    }
  }

  for (int t = 0; t < 128; ++t) {
    if (t == 64) {
      const float* wsrc = WTd + (size_t)(jbase + w * 4) * 1024;
#pragma unroll
      for (int i = 0; i < 4; ++i) {
        int g = l + 64 * i;
#pragma unroll
        for (int ji = 0; ji < 4; ++ji)
          wreg[i][ji] = *(const float4*)(wsrc + (size_t)ji * 1024 + g * 4);
      }
    }
    const bool enc = (t < 64);
    const int s = t & 63;
    const float* __restrict__ h_in = (t & 1) ? hB : hA;
    float* __restrict__ h_out = (t & 1) ? hA : hB;
    const float* __restrict__ x = enc ? xe : xd;

    float xv = x[((size_t)gb * 64 + s) * H_ + gj];

    {
      const float* hsrc = h_in + bg * H_;
      float v[8];
#pragma unroll
      for (int u = 0; u < 8; ++u)
        v[u] = __hip_atomic_load(hsrc + u * 512 + tid, __ATOMIC_RELAXED,
                                 __HIP_MEMORY_SCOPE_AGENT);
#pragma unroll
      for (int u = 0; u < 8; ++u)
        hl[u * 512 + tid] = v[u];
    }
    __syncthreads();

    double acc[4][4];
#pragma unroll
    for (int bi = 0; bi < 4; ++bi)
#pragma unroll
      for (int ji = 0; ji < 4; ++ji) acc[bi][ji] = 0.;

#pragma unroll
    for (int i = 0; i < 4; ++i) {
      int g = l + 64 * i;
      float4 hv[4];
#pragma unroll
      for (int bi = 0; bi < 4; ++bi)
        hv[bi] = *(const float4*)(hl + bi * 1024 + g * 4);
#pragma unroll
      for (int bi = 0; bi < 4; ++bi)
#pragma unroll
        for (int ji = 0; ji < 4; ++ji) {
          acc[bi][ji] = fma((double)hv[bi].x, (double)wreg[i][ji].x, acc[bi][ji]);
          acc[bi][ji] = fma((double)hv[bi].y, (double)wreg[i][ji].y, acc[bi][ji]);
          acc[bi][ji] = fma((double)hv[bi].z, (double)wreg[i][ji].z, acc[bi][ji]);
          acc[bi][ji] = fma((double)hv[bi].w, (double)wreg[i][ji].w, acc[bi][ji]);
        }
    }

    double r8[8], r4[4], r2[2], r1;
#pragma unroll
    for (int aa = 0; aa < 8; ++aa) {
      double send = (l & 1) ? acc[aa >> 2][aa & 3] : acc[(aa + 8) >> 2][(aa + 8) & 3];
      double mine = (l & 1) ? acc[(aa + 8) >> 2][(aa + 8) & 3] : acc[aa >> 2][aa & 3];
      r8[aa] = mine + __shfl_xor(send, 1);
    }
#pragma unroll
    for (int aa = 0; aa < 4; ++aa) {
      double send = (l & 2) ? r8[aa] : r8[aa + 4];
      double mine = (l & 2) ? r8[aa + 4] : r8[aa];
      r4[aa] = mine + __shfl_xor(send, 2);
    }
#pragma unroll
    for (int aa = 0; aa < 2; ++aa) {
      double send = (l & 4) ? r4[aa] : r4[aa + 2];
      double mine = (l & 4) ? r4[aa + 2] : r4[aa];
      r2[aa] = mine + __shfl_xor(send, 4);
    }
    {
      double send = (l & 8) ? r2[0] : r2[1];
      double mine = (l & 8) ? r2[1] : r2[0];
      r1 = mine + __shfl_xor(send, 8);
    }
    r1 += __shfl_xor(r1, 16);
    r1 += __shfl_xor(r1, 32);

    float hf = 0.f;
    if (l < 16) {
      double v = r1 + (double)xv + (double)(enc ? bje : bjd);
      double h = tanh(v);
      hf = (float)h;
      __hip_atomic_store(&h_out[(size_t)gb * H_ + gj], hf, __ATOMIC_RELAXED,
                         __HIP_MEMORY_SCOPE_AGENT);
    }

    if (t < 127) {
      asm volatile("s_waitcnt vmcnt(0)" ::: "memory");  // h stores ack'd
      __syncthreads();
      if (tid == 0) {
        __hip_atomic_fetch_add(mybar, 1u, __ATOMIC_RELAXED,
                               __HIP_MEMORY_SCOPE_AGENT);
        unsigned tgt = 32u * (unsigned)(t + 1);
        while (__hip_atomic_load(mybar, __ATOMIC_RELAXED,
                                 __HIP_MEMORY_SCOPE_AGENT) < tgt)
          __builtin_amdgcn_s_sleep(1);
      }
      __syncthreads();
    }
    if (!enc && l < 16)
      __builtin_nontemporal_store(f2bf(hf),
                                  &hsb[(size_t)s * (B_ * H_) + (size_t)gb * H_ + gj]);
  }
}

// ---------- log-softmax, row staged in LDS (one HBM read + one write) ----------
__global__ __launch_bounds__(1024)
void log_softmax_rows(float* __restrict__ out) {
  __shared__ float rl[32000];  // 125 KB row stage
  __shared__ float wm[16], wsv[16];
  float* row = out + (size_t)blockIdx.x * V_;
  const int tid = threadIdx.x;
  float m = -INFINITY, s = 0.f;
  for (int i = tid; i < V_ / 4; i += 1024) {
    float4 v = *(const float4*)(row + i * 4);
    *(float4*)(rl + i * 4) = v;
    float mx = fmaxf(fmaxf(v.x, v.y), fmaxf(v.z, v.w));
    if (mx > m) { s *= __expf(m - mx); m = mx; }
    s += __expf(v.x - m) + __expf(v.y - m) + __expf(v.z - m) + __expf(v.w - m);
  }
#pragma unroll
  for (int o = 32; o; o >>= 1) {
    float mo = __shfl_xor(m, o);
    float so = __shfl_xor(s, o);
    float mn = fmaxf(m, mo);
    s = s * __expf(m - mn) + so * __expf(mo - mn);
    m = mn;
  }
  int wv = tid >> 6;
  if ((tid & 63) == 0) { wm[wv] = m; wsv[wv] = s; }
  __syncthreads();
  float M = wm[0];
#pragma unroll
  for (int i = 1; i < 16; ++i) M = fmaxf(M, wm[i]);
  float Ssum = 0.f;
#pragma unroll
  for (int i = 0; i < 16; ++i) Ssum += wsv[i] * __expf(wm[i] - M);
  float L = M + logf(Ssum);
  for (int i = tid; i < V_ / 4; i += 1024) {
    float4 v = *(const float4*)(rl + i * 4);
    v.x -= L; v.y -= L; v.z -= L; v.w -= L;
    __builtin_nontemporal_store(v.x, &row[i * 4 + 0]);
    __builtin_nontemporal_store(v.y, &row[i * 4 + 1]);
    __builtin_nontemporal_store(v.z, &row[i * 4 + 2]);
    __builtin_nontemporal_store(v.w, &row[i * 4 + 3]);
  }
}

extern "C" void kernel_launch(void* const* d_in, const int* in_sizes, int n_in,
                              void* d_out, int out_size, void* d_ws, size_t ws_size,
                              hipStream_t stream) {
  const int*   src  = (const int*)  d_in[0];
  const int*   tgt  = (const int*)  d_in[1];
  const float* encE = (const float*)d_in[2];
  const float* decE = (const float*)d_in[3];
  const float* WihE = (const float*)d_in[4];
  const float* bihE = (const float*)d_in[5];
  const float* WhhE = (const float*)d_in[6];
  const float* bhhE = (const float*)d_in[7];
  const float* WihD = (const float*)d_in[8];
  const float* bihD = (const float*)d_in[9];
  const float* WhhD = (const float*)d_in[10];
  const float* bhhD = (const float*)d_in[11];
  const float* Wout = (const float*)d_in[12];
  const float* bout = (const float*)d_in[13];
  float* out = (float*)d_out;

  char* w = (char*)d_ws;
  float* x_e = (float*)w;                      w += (size_t)2048 * 1024 * 4;
  float* x_d = (float*)w;                      w += (size_t)2048 * 1024 * 4;
  float* h0  = (float*)w;                      w += 32 * 1024 * 4;
  float* h1  = (float*)w;                      w += 32 * 1024 * 4;
  unsigned* bar = (unsigned*)w;                w += 8 * 32 * 4;  // 8 counters, 128B apart
  float* WhhTe = (float*)w;                    w += (size_t)1024 * 1024 * 4;
  float* WhhTd = (float*)w;                    w += (size_t)1024 * 1024 * 4;
  unsigned short* hsb   = (unsigned short*)w;  w += (size_t)2048 * 1024 * 2;
  unsigned short* WoutT = (unsigned short*)w;  w += (size_t)V_ * 1024 * 2;

  // Fused prologue: dual embed-dgemm + all weight transposes in ONE launch
  prologue<<<9536, 256, 0, stream>>>(src, encE, WihE, bihE, x_e,
                                     tgt, decE, WihD, bihD, x_d,
                                     WhhE, WhhTe, WhhD, WhhTd, Wout, WoutT);

  // Persistent group-local scan (8 independent 4-batch chains)
  hipMemsetAsync(h0, 0, 32 * 1024 * 4, stream);
  hipMemsetAsync(bar, 0, 8 * 32 * 4, stream);
  rnn_scan_grp2<<<256, 512, 0, stream>>>(x_e, x_d, WhhTe, WhhTd, bhhE, bhhD,
                                         h0, h1, hsb, bar);

  // Logits: out[b][t][:] = hs[t*B+b] @ Wout + bout  (bf16 MFMA, raw logits)
  gemm_bt_swap<<<(2048 / 128) * (V_ / 128), 256, 0, stream>>>(hsb, WoutT, bout, out,
                                                              2048, V_, H_);
  // In-place log-softmax
  log_softmax_rows<<<B_ * T_, 1024, 0, stream>>>(out);
}

// Round 20
// 955.571 us; speedup vs baseline: 1.0453x; 1.0019x over previous
//
#include <hip/hip_runtime.h>
#include <hip/hip_bf16.h>
#include <math.h>

#define B_ 32
#define S_ 64
#define T_ 64
#define V_ 32000
#define E_ 512
#define H_ 1024

typedef __attribute__((ext_vector_type(8))) short short8;
typedef __attribute__((ext_vector_type(4))) float f32x4;

static __device__ __forceinline__ unsigned short f2bf(float f) {
  union { float f; unsigned u; } c; c.f = f;
  unsigned r = (c.u + 0x7fffu + ((c.u >> 16) & 1u)) >> 16;  // RNE
  return (unsigned short)r;
}

// ---------- fused prologue: dual embed-dgemm + transposes + scan-state init ----------
//   [0, 1024)      : dual f64-accum embed GEMM (x_e / x_d)        [compute]
//   [1024, 1536)   : transpose_f32 of WhhE/WhhD -> WhhT           [HBM]
//   [1536, 9536)   : transpose fp32->bf16 of Wout -> WoutT        [HBM]
//   [9536]         : zero h0 + barrier counters (replaces 2 memset dispatches)
__global__ __launch_bounds__(256)
void prologue(const int* __restrict__ src, const float* __restrict__ encE,
              const float* __restrict__ WihE, const float* __restrict__ bihE,
              float* __restrict__ x_e,
              const int* __restrict__ tgt, const float* __restrict__ decE,
              const float* __restrict__ WihD, const float* __restrict__ bihD,
              float* __restrict__ x_d,
              const float* __restrict__ WhhE, float* __restrict__ WhhTe,
              const float* __restrict__ WhhD, float* __restrict__ WhhTd,
              const float* __restrict__ Wout, unsigned short* __restrict__ WoutT,
              float* __restrict__ h0, unsigned* __restrict__ bar) {
  __shared__ float smem[4224];
  const int bid = blockIdx.x;
  const int tid = threadIdx.x;

  if (bid < 1024) {
    // ---- dual embed dgemm ----
    const int half = bid >> 9;
    const int b9 = bid & 511;
    const int* __restrict__ idx = half ? tgt : src;
    const float* __restrict__ emb = half ? decE : encE;
    const float* __restrict__ Bm = half ? WihD : WihE;
    const float* __restrict__ bias = half ? bihD : bihE;
    float* __restrict__ C = half ? x_d : x_e;
    float (*As)[68] = (float(*)[68])smem;
    float (*Bs)[64] = (float(*)[64])(smem + 32 * 68);
    const int bm = b9 & 31;
    const int bn = b9 >> 5;
    const int tr = tid >> 4, tc = tid & 15;

    const int arow = tid >> 3, acol = (tid & 7) * 4;
    const float* arp[2];
#pragma unroll
    for (int p = 0; p < 2; ++p)
      arp[p] = emb + (size_t)idx[bm * 64 + arow + p * 32] * E_;

    double acc[4][4] = {};
    for (int kt = 0; kt < E_; kt += 32) {
#pragma unroll
      for (int p = 0; p < 2; ++p) {
        int r = arow + p * 32;
        float4 v = *(const float4*)(arp[p] + kt + acol);
        As[acol + 0][r] = v.x; As[acol + 1][r] = v.y;
        As[acol + 2][r] = v.z; As[acol + 3][r] = v.w;
      }
      int brow = tid >> 4, bcol = (tid & 15) * 4;
#pragma unroll
      for (int p = 0; p < 2; ++p) {
        int r = brow + p * 16;
        float4 v = *(const float4*)(Bm + (size_t)(kt + r) * H_ + bn * 64 + bcol);
        *(float4*)(&Bs[r][bcol]) = v;
      }
      __syncthreads();
#pragma unroll
      for (int k = 0; k < 32; ++k) {
        float4 av = *(const float4*)(&As[k][tr * 4]);
        float4 bv = *(const float4*)(&Bs[k][tc * 4]);
        double a[4] = {(double)av.x, (double)av.y, (double)av.z, (double)av.w};
        double b[4] = {(double)bv.x, (double)bv.y, (double)bv.z, (double)bv.w};
#pragma unroll
        for (int i = 0; i < 4; ++i)
#pragma unroll
          for (int j = 0; j < 4; ++j) acc[i][j] = fma(a[i], b[j], acc[i][j]);
      }
      __syncthreads();
    }
#pragma unroll
    for (int i = 0; i < 4; ++i) {
      int gm = bm * 64 + tr * 4 + i;
      int gn = bn * 64 + tc * 4;
      float4 o;
      o.x = (float)(acc[i][0] + (double)bias[gn + 0]);
      o.y = (float)(acc[i][1] + (double)bias[gn + 1]);
      o.z = (float)(acc[i][2] + (double)bias[gn + 2]);
      o.w = (float)(acc[i][3] + (double)bias[gn + 3]);
      *(float4*)(C + (size_t)gm * H_ + gn) = o;
    }
  } else if (bid < 1536) {
    // ---- Whh transposes (f32) ----
    int t6 = bid - 1024;
    int k0 = (t6 & 15) * 64;
    int byf = t6 >> 4;
    const float* __restrict__ W = (byf >> 4) ? WhhD : WhhE;
    float* __restrict__ WT = (byf >> 4) ? WhhTd : WhhTe;
    int n0 = (byf & 15) * 64;
    float (*tld)[65] = (float(*)[65])smem;
    int r = tid >> 4, c4 = tid & 15;
#pragma unroll
    for (int i = 0; i < 4; ++i) {
      int row = r + i * 16;
      float4 v = *(const float4*)(W + (size_t)(k0 + row) * H_ + n0 + c4 * 4);
      tld[row][c4 * 4 + 0] = v.x; tld[row][c4 * 4 + 1] = v.y;
      tld[row][c4 * 4 + 2] = v.z; tld[row][c4 * 4 + 3] = v.w;
    }
    __syncthreads();
#pragma unroll
    for (int i = 0; i < 4; ++i) {
      int n = r + i * 16;
      float4 o;
      o.x = tld[c4 * 4 + 0][n]; o.y = tld[c4 * 4 + 1][n];
      o.z = tld[c4 * 4 + 2][n]; o.w = tld[c4 * 4 + 3][n];
      *(float4*)(WT + (size_t)(n0 + n) * H_ + k0 + c4 * 4) = o;
    }
  } else if (bid < 9536) {
    // ---- Wout transpose fp32 -> bf16 ----
    int t6 = bid - 1536;
    int k0 = (t6 & 15) * 64;
    int n0 = (t6 >> 4) * 64;
    float (*tld)[65] = (float(*)[65])smem;
    int r = tid >> 4, c4 = tid & 15;
#pragma unroll
    for (int i = 0; i < 4; ++i) {
      int row = r + i * 16;
      float4 v = *(const float4*)(Wout + (size_t)(k0 + row) * V_ + n0 + c4 * 4);
      tld[row][c4 * 4 + 0] = v.x; tld[row][c4 * 4 + 1] = v.y;
      tld[row][c4 * 4 + 2] = v.z; tld[row][c4 * 4 + 3] = v.w;
    }
    __syncthreads();
#pragma unroll
    for (int i = 0; i < 4; ++i) {
      int n = r + i * 16;
      ushort4 o;
      o.x = f2bf(tld[c4 * 4 + 0][n]); o.y = f2bf(tld[c4 * 4 + 1][n]);
      o.z = f2bf(tld[c4 * 4 + 2][n]); o.w = f2bf(tld[c4 * 4 + 3][n]);
      *(ushort4*)(WoutT + (size_t)(n0 + n) * H_ + k0 + c4 * 4) = o;
    }
  } else {
    // ---- scan-state init: h0 = 0 (32K floats), bar = 0 (256 uints) ----
    float4 z = make_float4(0.f, 0.f, 0.f, 0.f);
#pragma unroll
    for (int p = 0; p < 32; ++p)
      *(float4*)(h0 + (p * 256 + tid) * 4) = z;
    if (tid < 256) bar[tid] = 0u;
  }
}

// ---------- bf16 MFMA GEMM: C[M,N] = A[M,K] * BT[N,K]^T + bias ----------
// 128x128 tile, XOR-swizzled LDS, XCD swizzle, T14 reg-prefetch, LDS-staged
// coalesced epilogue (r17 proven form, FROZEN).
__global__ __launch_bounds__(256)
void gemm_bt_swap(const unsigned short* __restrict__ A, const unsigned short* __restrict__ BT,
                  const float* __restrict__ bias, float* __restrict__ C,
                  int M, int N, int K) {
  __shared__ unsigned short AsBs[2][128 * 64];
  unsigned short* As = AsBs[0];
  unsigned short* Bs = AsBs[1];
  const int nbm = M >> 7;
  int idx = blockIdx.x;
  const int cpx = gridDim.x >> 3;
  idx = (idx & 7) * cpx + (idx >> 3);
  const int bm = idx % nbm;
  const int bn = idx / nbm;
  const int tid = threadIdx.x;
  const int lane = tid & 63;
  const int wr = (tid >> 6) >> 1;
  const int wc = (tid >> 6) & 1;

  f32x4 acc[4][4] = {};

  int srow[4], scol8[4], ssw[4];
#pragma unroll
  for (int i = 0; i < 4; ++i) {
    int c = i * 256 + tid;
    srow[i] = c >> 3; scol8[i] = c & 7;
    ssw[i] = scol8[i] ^ (srow[i] & 7);
  }

  short8 av[4], bv[4];
#pragma unroll
  for (int i = 0; i < 4; ++i) {
    av[i] = *(const short8*)(A + (size_t)(bm * 128 + srow[i]) * K + scol8[i] * 8);
    bv[i] = *(const short8*)(BT + (size_t)(bn * 128 + srow[i]) * K + scol8[i] * 8);
  }

  for (int kt = 0; kt < K; kt += 64) {
#pragma unroll
    for (int i = 0; i < 4; ++i) {
      *(short8*)(As + srow[i] * 64 + ssw[i] * 8) = av[i];
      *(short8*)(Bs + srow[i] * 64 + ssw[i] * 8) = bv[i];
    }
    __syncthreads();

    if (kt + 64 < K) {
#pragma unroll
      for (int i = 0; i < 4; ++i) {
        av[i] = *(const short8*)(A + (size_t)(bm * 128 + srow[i]) * K + kt + 64 + scol8[i] * 8);
        bv[i] = *(const short8*)(BT + (size_t)(bn * 128 + srow[i]) * K + kt + 64 + scol8[i] * 8);
      }
    }

#pragma unroll
    for (int kk = 0; kk < 64; kk += 32) {
      int kc = (kk + ((lane >> 4) << 3)) >> 3;
      short8 af[4], bfr[4];
#pragma unroll
      for (int mi = 0; mi < 4; ++mi) {
        int row = wr * 64 + mi * 16 + (lane & 15);
        af[mi] = *(const short8*)(As + row * 64 + ((kc ^ (row & 7)) << 3));
      }
#pragma unroll
      for (int ni = 0; ni < 4; ++ni) {
        int row = wc * 64 + ni * 16 + (lane & 15);
        bfr[ni] = *(const short8*)(Bs + row * 64 + ((kc ^ (row & 7)) << 3));
      }
#pragma unroll
      for (int mi = 0; mi < 4; ++mi)
#pragma unroll
        for (int ni = 0; ni < 4; ++ni)
          acc[mi][ni] = __builtin_amdgcn_mfma_f32_16x16x32_bf16(
              af[mi], bfr[ni], acc[mi][ni], 0, 0, 0);
    }
    __syncthreads();
  }

  float* Ct = (float*)AsBs;  // 32 x 132 f32 (staging LDS is dead)
  const int cq = (lane >> 4) << 2;
  const int cn = lane & 15;
#pragma unroll
  for (int mi = 0; mi < 4; ++mi) {
    if (mi) __syncthreads();
#pragma unroll
    for (int ni = 0; ni < 4; ++ni) {
      int gn = bn * 128 + wc * 64 + ni * 16 + cn;
      float bvv = bias[gn];
#pragma unroll
      for (int q = 0; q < 4; ++q)
        Ct[(wr * 16 + cq + q) * 132 + wc * 64 + ni * 16 + cn] =
            acc[mi][ni][q] + bvv;
    }
    __syncthreads();
#pragma unroll
    for (int p = 0; p < 4; ++p) {
      int f = p * 256 + tid;
      int r = f >> 5, c4 = f & 31;
      float4 v = *(const float4*)(Ct + r * 132 + c4 * 4);
      int gm = bm * 128 + (r >> 4) * 64 + mi * 16 + (r & 15);
      int b = gm & (B_ - 1);
      int t = gm >> 5;
      float* dstp = &C[((size_t)b * T_ + t) * N + bn * 128 + c4 * 4];
      __builtin_nontemporal_store(v.x, dstp + 0);
      __builtin_nontemporal_store(v.y, dstp + 1);
      __builtin_nontemporal_store(v.z, dstp + 2);
      __builtin_nontemporal_store(v.w, dstp + 3);
    }
  }
}

// ---------- persistent group-local RNN scan (r12/r17 frozen structure) ----------
// Only change: wreg pre-converted to f64 REGISTERS (weights are step-
// invariant; the old form re-converted f32->f64 64x/thread/step). Exact
// conversion + unchanged FMA order -> bit-identical trajectory.
__global__ __launch_bounds__(512)
void rnn_scan_grp2(const float* __restrict__ xe, const float* __restrict__ xd,
                   const float* __restrict__ WTe, const float* __restrict__ WTd,
                   const float* __restrict__ bhhE, const float* __restrict__ bhhD,
                   float* __restrict__ hA, float* __restrict__ hB,
                   unsigned short* __restrict__ hsb, unsigned* __restrict__ bar) {
  __shared__ float hl[4 * 1024];  // 16 KB chain h-slice
  const int tid = threadIdx.x;
  const int grp = blockIdx.x & 7;
  const int jslot = blockIdx.x >> 3;
  const int jbase = jslot * 32;
  const int bg = grp * 4;
  const int w = tid >> 6;  // wave -> j-quad
  const int l = tid & 63;  // k-split lane
  unsigned* mybar = bar + grp * 32;  // 128B-spaced counters

  const int a = 8 * (l & 1) + 4 * ((l >> 1) & 1) + 2 * ((l >> 2) & 1) +
                ((l >> 3) & 1);
  const int lb = a >> 2;
  const int gb = bg + lb;
  const int gj = jbase + w * 4 + (a & 3);
  const float bje = bhhE[gj];
  const float bjd = bhhD[gj];

  // W fragments in f64 registers (pre-converted once; exact)
  double wrd[4][4][4];
  {
    const float* wsrc = WTe + (size_t)(jbase + w * 4) * 1024;
#pragma unroll
    for (int i = 0; i < 4; ++i) {
      int g = l + 64 * i;
#pragma unroll
      for (int ji = 0; ji < 4; ++ji) {
        float4 v = *(const float4*)(wsrc + (size_t)ji * 1024 + g * 4);
        wrd[i][ji][0] = (double)v.x; wrd[i][ji][1] = (double)v.y;
        wrd[i][ji][2] = (double)v.z; wrd[i][ji][3] = (double)v.w;
      }
    }
  }

  for (int t = 0; t < 128; ++t) {
    if (t == 64) {  // decoder weights (one-time reload + convert)
      const float* wsrc = WTd + (size_t)(jbase + w * 4) * 1024;
#pragma unroll
      for (int i = 0; i < 4; ++i) {
        int g = l + 64 * i;
#pragma unroll
        for (int ji = 0; ji < 4; ++ji) {
          float4 v = *(const float4*)(wsrc + (size_t)ji * 1024 + g * 4);
          wrd[i][ji][0] = (double)v.x; wrd[i][ji][1] = (double)v.y;
          wrd[i][ji][2] = (double)v.z; wrd[i][ji][3] = (double)v.w;
        }
      }
    }
    const bool enc = (t < 64);
    const int s = t & 63;
    const float* __restrict__ h_in = (t & 1) ? hB : hA;
    float* __restrict__ h_out = (t & 1) ? hA : hB;
    const float* __restrict__ x = enc ? xe : xd;

    float xv = x[((size_t)gb * 64 + s) * H_ + gj];

    {
      const float* hsrc = h_in + bg * H_;
      float v[8];
#pragma unroll
      for (int u = 0; u < 8; ++u)
        v[u] = __hip_atomic_load(hsrc + u * 512 + tid, __ATOMIC_RELAXED,
                                 __HIP_MEMORY_SCOPE_AGENT);
#pragma unroll
      for (int u = 0; u < 8; ++u)
        hl[u * 512 + tid] = v[u];
    }
    __syncthreads();

    double acc[4][4];
#pragma unroll
    for (int bi = 0; bi < 4; ++bi)
#pragma unroll
      for (int ji = 0; ji < 4; ++ji) acc[bi][ji] = 0.;

#pragma unroll
    for (int i = 0; i < 4; ++i) {
      int g = l + 64 * i;
      float4 hv[4];
#pragma unroll
      for (int bi = 0; bi < 4; ++bi)
        hv[bi] = *(const float4*)(hl + bi * 1024 + g * 4);
#pragma unroll
      for (int bi = 0; bi < 4; ++bi)
#pragma unroll
        for (int ji = 0; ji < 4; ++ji) {
          acc[bi][ji] = fma((double)hv[bi].x, wrd[i][ji][0], acc[bi][ji]);
          acc[bi][ji] = fma((double)hv[bi].y, wrd[i][ji][1], acc[bi][ji]);
          acc[bi][ji] = fma((double)hv[bi].z, wrd[i][ji][2], acc[bi][ji]);
          acc[bi][ji] = fma((double)hv[bi].w, wrd[i][ji][3], acc[bi][ji]);
        }
    }

    double r8[8], r4[4], r2[2], r1;
#pragma unroll
    for (int aa = 0; aa < 8; ++aa) {
      double send = (l & 1) ? acc[aa >> 2][aa & 3] : acc[(aa + 8) >> 2][(aa + 8) & 3];
      double mine = (l & 1) ? acc[(aa + 8) >> 2][(aa + 8) & 3] : acc[aa >> 2][aa & 3];
      r8[aa] = mine + __shfl_xor(send, 1);
    }
#pragma unroll
    for (int aa = 0; aa < 4; ++aa) {
      double send = (l & 2) ? r8[aa] : r8[aa + 4];
      double mine = (l & 2) ? r8[aa + 4] : r8[aa];
      r4[aa] = mine + __shfl_xor(send, 2);
    }
#pragma unroll
    for (int aa = 0; aa < 2; ++aa) {
      double send = (l & 4) ? r4[aa] : r4[aa + 2];
      double mine = (l & 4) ? r4[aa + 2] : r4[aa];
      r2[aa] = mine + __shfl_xor(send, 4);
    }
    {
      double send = (l & 8) ? r2[0] : r2[1];
      double mine = (l & 8) ? r2[1] : r2[0];
      r1 = mine + __shfl_xor(send, 8);
    }
    r1 += __shfl_xor(r1, 16);
    r1 += __shfl_xor(r1, 32);

    float hf = 0.f;
    if (l < 16) {
      double v = r1 + (double)xv + (double)(enc ? bje : bjd);
      double h = tanh(v);
      hf = (float)h;
      __hip_atomic_store(&h_out[(size_t)gb * H_ + gj], hf, __ATOMIC_RELAXED,
                         __HIP_MEMORY_SCOPE_AGENT);
    }

    if (t < 127) {
      asm volatile("s_waitcnt vmcnt(0)" ::: "memory");  // h stores ack'd
      __syncthreads();
      if (tid == 0) {
        __hip_atomic_fetch_add(mybar, 1u, __ATOMIC_RELAXED,
                               __HIP_MEMORY_SCOPE_AGENT);
        unsigned tgt = 32u * (unsigned)(t + 1);
        while (__hip_atomic_load(mybar, __ATOMIC_RELAXED,
                                 __HIP_MEMORY_SCOPE_AGENT) < tgt)
          __builtin_amdgcn_s_sleep(1);
      }
      __syncthreads();
    }
    if (!enc && l < 16)
      __builtin_nontemporal_store(f2bf(hf),
                                  &hsb[(size_t)s * (B_ * H_) + (size_t)gb * H_ + gj]);
  }
}

// ---------- log-softmax, row staged in LDS (one HBM read + one write) ----------
__global__ __launch_bounds__(1024)
void log_softmax_rows(float* __restrict__ out) {
  __shared__ float rl[32000];  // 125 KB row stage
  __shared__ float wm[16], wsv[16];
  float* row = out + (size_t)blockIdx.x * V_;
  const int tid = threadIdx.x;
  float m = -INFINITY, s = 0.f;
  for (int i = tid; i < V_ / 4; i += 1024) {
    float4 v = *(const float4*)(row + i * 4);
    *(float4*)(rl + i * 4) = v;
    float mx = fmaxf(fmaxf(v.x, v.y), fmaxf(v.z, v.w));
    if (mx > m) { s *= __expf(m - mx); m = mx; }
    s += __expf(v.x - m) + __expf(v.y - m) + __expf(v.z - m) + __expf(v.w - m);
  }
#pragma unroll
  for (int o = 32; o; o >>= 1) {
    float mo = __shfl_xor(m, o);
    float so = __shfl_xor(s, o);
    float mn = fmaxf(m, mo);
    s = s * __expf(m - mn) + so * __expf(mo - mn);
    m = mn;
  }
  int wv = tid >> 6;
  if ((tid & 63) == 0) { wm[wv] = m; wsv[wv] = s; }
  __syncthreads();
  float M = wm[0];
#pragma unroll
  for (int i = 1; i < 16; ++i) M = fmaxf(M, wm[i]);
  float Ssum = 0.f;
#pragma unroll
  for (int i = 0; i < 16; ++i) Ssum += wsv[i] * __expf(wm[i] - M);
  float L = M + logf(Ssum);
  for (int i = tid; i < V_ / 4; i += 1024) {
    float4 v = *(const float4*)(rl + i * 4);
    v.x -= L; v.y -= L; v.z -= L; v.w -= L;
    __builtin_nontemporal_store(v.x, &row[i * 4 + 0]);
    __builtin_nontemporal_store(v.y, &row[i * 4 + 1]);
    __builtin_nontemporal_store(v.z, &row[i * 4 + 2]);
    __builtin_nontemporal_store(v.w, &row[i * 4 + 3]);
  }
}

extern "C" void kernel_launch(void* const* d_in, const int* in_sizes, int n_in,
                              void* d_out, int out_size, void* d_ws, size_t ws_size,
                              hipStream_t stream) {
  const int*   src  = (const int*)  d_in[0];
  const int*   tgt  = (const int*)  d_in[1];
  const float* encE = (const float*)d_in[2];
  const float* decE = (const float*)d_in[3];
  const float* WihE = (const float*)d_in[4];
  const float* bihE = (const float*)d_in[5];
  const float* WhhE = (const float*)d_in[6];
  const float* bhhE = (const float*)d_in[7];
  const float* WihD = (const float*)d_in[8];
  const float* bihD = (const float*)d_in[9];
  const float* WhhD = (const float*)d_in[10];
  const float* bhhD = (const float*)d_in[11];
  const float* Wout = (const float*)d_in[12];
  const float* bout = (const float*)d_in[13];
  float* out = (float*)d_out;

  char* w = (char*)d_ws;
  float* x_e = (float*)w;                      w += (size_t)2048 * 1024 * 4;
  float* x_d = (float*)w;                      w += (size_t)2048 * 1024 * 4;
  float* h0  = (float*)w;                      w += 32 * 1024 * 4;
  float* h1  = (float*)w;                      w += 32 * 1024 * 4;
  unsigned* bar = (unsigned*)w;                w += 8 * 32 * 4;  // 8 counters, 128B apart
  float* WhhTe = (float*)w;                    w += (size_t)1024 * 1024 * 4;
  float* WhhTd = (float*)w;                    w += (size_t)1024 * 1024 * 4;
  unsigned short* hsb   = (unsigned short*)w;  w += (size_t)2048 * 1024 * 2;
  unsigned short* WoutT = (unsigned short*)w;  w += (size_t)V_ * 1024 * 2;

  // Fused prologue: dual embed-dgemm + all transposes + scan-state init
  prologue<<<9537, 256, 0, stream>>>(src, encE, WihE, bihE, x_e,
                                     tgt, decE, WihD, bihD, x_d,
                                     WhhE, WhhTe, WhhD, WhhTd, Wout, WoutT,
                                     h0, bar);

  // Persistent group-local scan (8 independent 4-batch chains)
  rnn_scan_grp2<<<256, 512, 0, stream>>>(x_e, x_d, WhhTe, WhhTd, bhhE, bhhD,
                                         h0, h1, hsb, bar);

  // Logits: out[b][t][:] = hs[t*B+b] @ Wout + bout  (bf16 MFMA, raw logits)
  gemm_bt_swap<<<(2048 / 128) * (V_ / 128), 256, 0, stream>>>(hsb, WoutT, bout, out,
                                                              2048, V_, H_);
  // In-place log-softmax
  log_softmax_rows<<<B_ * T_, 1024, 0, stream>>>(out);
}